// Round 14
// baseline (5431.253 us; speedup 1.0000x reference)
//
#include <hip/hip_runtime.h>
#include <hip/hip_bf16.h>

#define NB   64     // batch
#define NS   128    // seq len
#define ND   256    // embed dim
#define NU   512    // hidden units
#define N3   1536   // 3*NU

typedef __attribute__((ext_vector_type(4))) float  f32x4;
typedef __attribute__((ext_vector_type(8))) short  s16x8;
typedef unsigned long long u64;
typedef unsigned int       u32;
typedef unsigned short     u16;

__device__ __forceinline__ u16 f2bf(float v) {
  unsigned u = __builtin_bit_cast(unsigned, v);
  u += 0x7fffu + ((u >> 16) & 1u);          // round-to-nearest-even
  return (u16)(u >> 16);
}

// -------- Rbf[c][k] = bf16(R[k][c]) : tiled LDS transpose ----------------------
__global__ __launch_bounds__(256) void rtrans_kernel(const float* __restrict__ R,
                                                     u16* __restrict__ Rbf) {
  __shared__ float ld[64][65];
  const int c0 = blockIdx.x * 64;      // 24 tiles
  const int k0 = blockIdx.y * 64;      // 8 tiles
  const int tx = threadIdx.x & 63, ty = threadIdx.x >> 6;   // ty 0..3
  #pragma unroll
  for (int r = 0; r < 16; ++r) {
    const int k = ty + r * 4;
    ld[k][tx] = R[(size_t)(k0 + k) * N3 + c0 + tx];
  }
  __syncthreads();
  #pragma unroll
  for (int r = 0; r < 16; ++r) {
    const int c = ty + r * 4;
    Rbf[(size_t)(c0 + c) * NU + k0 + tx] = f2bf(ld[tx][c]);
  }
}

// -------- phase 1: xp = gather(emb,x) @ W + b_in  (f32 SIMT, unchanged) --------
__global__ __launch_bounds__(256) void xproj_kernel(
    const int* __restrict__ x, const float* __restrict__ emb,
    const float* __restrict__ W, const float* __restrict__ bias,
    float* __restrict__ xp) {
  __shared__ float As[32][68];
  __shared__ float Bs[32][68];
  __shared__ int tok[64];
  const int tid = threadIdx.x;
  const int m0 = blockIdx.y * 64;
  const int n0 = blockIdx.x * 64;
  if (tid < 64) tok[tid] = x[m0 + tid];
  __syncthreads();
  const int tx = tid & 15, ty = tid >> 4;
  float acc[4][4] = {};
  for (int k0 = 0; k0 < ND; k0 += 32) {
    {
      const int m = tid & 63, kq = tid >> 6;
      const float* src = emb + (size_t)tok[m] * ND + k0 + kq * 8;
      const float4 v0 = *(const float4*)(src);
      const float4 v1 = *(const float4*)(src + 4);
      As[kq*8+0][m] = v0.x; As[kq*8+1][m] = v0.y;
      As[kq*8+2][m] = v0.z; As[kq*8+3][m] = v0.w;
      As[kq*8+4][m] = v1.x; As[kq*8+5][m] = v1.y;
      As[kq*8+6][m] = v1.z; As[kq*8+7][m] = v1.w;
    }
    {
      const int n = (tid & 15) * 4, k = tid >> 4;
      *(float4*)&Bs[k][n]    = *(const float4*)&W[(size_t)(k0 + k) * N3 + n0 + n];
      *(float4*)&Bs[k+16][n] = *(const float4*)&W[(size_t)(k0 + k + 16) * N3 + n0 + n];
    }
    __syncthreads();
    #pragma unroll
    for (int kk = 0; kk < 32; ++kk) {
      const float4 b4 = *(const float4*)&Bs[kk][tx * 4];
      float a[4];
      #pragma unroll
      for (int i = 0; i < 4; ++i) a[i] = As[kk][ty * 4 + i];
      #pragma unroll
      for (int i = 0; i < 4; ++i) {
        acc[i][0] += a[i] * b4.x;
        acc[i][1] += a[i] * b4.y;
        acc[i][2] += a[i] * b4.z;
        acc[i][3] += a[i] * b4.w;
      }
    }
    __syncthreads();
  }
  #pragma unroll
  for (int i = 0; i < 4; ++i) {
    const size_t row = (size_t)(m0 + ty * 4 + i) * N3 + n0 + tx * 4;
    float4 o;
    o.x = acc[i][0] + bias[n0 + tx*4 + 0];
    o.y = acc[i][1] + bias[n0 + tx*4 + 1];
    o.z = acc[i][2] + bias[n0 + tx*4 + 2];
    o.w = acc[i][3] + bias[n0 + tx*4 + 3];
    *(float4*)&xp[row] = o;
  }
}

// -------- phase 2: single-CU-per-chain GRU scan; R in the register file --------
// 4 blocks x 1024 threads (16 waves, one CU each). Block g owns batch group g
// (16 batches) END-TO-END: h lives in an LDS double-buffer (bf16) + f32 master
// in registers; R^T lives in 384 VGPRs/wave of B-fragments (96 cols x 512 k).
// Per step: ds_read A-frags -> 96 MFMAs/wave -> f32 gates -> ds_write h[t+1] ->
// ONE __syncthreads. Zero inter-block communication: no flags, no atomics, no
// sentinels -> deadlock-impossible, and the 6us cross-CU sync floor is gone.
__global__ __launch_bounds__(1024, 1) void gru_scan_kernel(
    const float* __restrict__ xp, const float* __restrict__ hidden,
    const u16* __restrict__ Rbf, const float* __restrict__ bias,
    float* __restrict__ out) {
  __shared__ u16 hbuf[2][16][524];   // h double-buffer, padded rows

  const int g    = blockIdx.x;          // batch group 0..3
  const int tid  = threadIdx.x;
  const int wv   = tid >> 6;            // wave 0..15
  const int lane = tid & 63;
  const int u0w  = wv << 5;             // 32 units per wave
  const int ar   = lane & 15;           // A-frag row (batch)
  const int kg   = lane >> 4;           // k-group
  const int cu   = lane & 15;           // unit-in-tile (= D col)
  const int drow = kg << 2;             // D row base (batch)

  // ---- one-time: B fragments into registers: 6 tiles x 16 ks = 384 VGPRs ----
  s16x8 bfr[6][16];
  #pragma unroll
  for (int ug = 0; ug < 2; ++ug)
    #pragma unroll
    for (int gate = 0; gate < 3; ++gate) {
      const u16* base = Rbf + ((size_t)(gate << 9) + u0w + (ug << 4) + cu) * NU + (kg << 3);
      #pragma unroll
      for (int ks = 0; ks < 16; ++ks)
        bfr[ug * 3 + gate][ks] = *(const s16x8*)(base + (ks << 5));
    }

  // ---- h master (f32): 4 batches x 2 units per lane ----
  float hr[2][4];
  #pragma unroll
  for (int ug = 0; ug < 2; ++ug)
    #pragma unroll
    for (int i = 0; i < 4; ++i)
      hr[ug][i] = hidden[(size_t)((g << 4) + drow + i) * NU + u0w + (ug << 4) + cu];

  float bz[2], brr[2], bh[2];
  #pragma unroll
  for (int ug = 0; ug < 2; ++ug) {
    const int u = u0w + (ug << 4) + cu;
    bz[ug]  = bias[N3 + u];
    brr[ug] = bias[N3 + 512 + u];
    bh[ug]  = bias[N3 + 1024 + u];
  }

  // ---- stage hbuf[0] = bf16(hidden) for this group ----
  for (int i = tid; i < 16 * 512; i += 1024) {
    const int r = i >> 9, c = i & 511;
    hbuf[0][r][c] = f2bf(hidden[(size_t)((g << 4) + r) * NU + c]);
  }
  __syncthreads();

  // ---- per-step base addresses (advanced incrementally) ----
  const float* xb[4];   // -> xr gate (offsets -2048 / 0 / +2048 select gate)
  float*       ob[4];
  #pragma unroll
  for (int i = 0; i < 4; ++i) {
    const size_t b = (size_t)(g << 4) + drow + i;
    xb[i] = xp + (b * NS) * N3 + 512 + u0w + cu;
    ob[i] = out + (b * NS) * NU + u0w + cu;
  }

  for (int t = 0; t < NS; ++t) {
    const int cur = t & 1, nx = cur ^ 1;

    // xp loads: 4 batches x 3 gates x 2 units
    float xg[2][3][4];
    #pragma unroll
    for (int i = 0; i < 4; ++i)
      #pragma unroll
      for (int ug = 0; ug < 2; ++ug) {
        xg[ug][0][i] = xb[i][-512 + (ug << 4)];
        xg[ug][1][i] = xb[i][(ug << 4)];
        xg[ug][2][i] = xb[i][512 + (ug << 4)];
      }

    // 96 MFMAs: A from LDS (shared across the 6 tiles), B from registers
    f32x4 acc[6];
    #pragma unroll
    for (int j = 0; j < 6; ++j) acc[j] = (f32x4){0.f, 0.f, 0.f, 0.f};
    #pragma unroll
    for (int ks = 0; ks < 16; ++ks) {
      const s16x8 af = *(const s16x8*)&hbuf[cur][ar][(ks << 5) + (kg << 3)];
      #pragma unroll
      for (int j = 0; j < 6; ++j)
        acc[j] = __builtin_amdgcn_mfma_f32_16x16x32_bf16(af, bfr[j][ks], acc[j], 0, 0, 0);
    }

    // gates + state update: 8 (batch,unit) cells per lane
    #pragma unroll
    for (int ug = 0; ug < 2; ++ug) {
      #pragma unroll
      for (int i = 0; i < 4; ++i) {
        const float z = 1.f / (1.f + __expf(-(xg[ug][0][i] + acc[ug * 3 + 0][i] + bz[ug])));
        const float r = 1.f / (1.f + __expf(-(xg[ug][1][i] + acc[ug * 3 + 1][i] + brr[ug])));
        const float e = __expf(2.f * (xg[ug][2][i] + r * (acc[ug * 3 + 2][i] + bh[ug])));
        const float hh = 1.f - 2.f / (e + 1.f);      // tanh, never NaN/Inf
        const float hn = z * hr[ug][i] + (1.f - z) * hh;
        hr[ug][i] = hn;
        ob[i][(ug << 4)] = hn;                       // out[b][t][u]
        if (t < NS - 1)
          hbuf[nx][drow + i][u0w + (ug << 4) + cu] = f2bf(hn);
        else
          out[(size_t)NB * NS * NU + ((size_t)(g << 4) + drow + i) * NU
              + u0w + (ug << 4) + cu] = hn;          // final state tail
      }
    }
    __syncthreads();   // h[t+1] complete; also guards buffer swap WAR

    #pragma unroll
    for (int i = 0; i < 4; ++i) { xb[i] += N3; ob[i] += NU; }
  }
}

extern "C" void kernel_launch(void* const* d_in, const int* in_sizes, int n_in,
                              void* d_out, int out_size, void* d_ws, size_t ws_size,
                              hipStream_t stream) {
  const int*   x      = (const int*)d_in[0];
  const float* hidden = (const float*)d_in[1];
  const float* emb    = (const float*)d_in[2];
  const float* W      = (const float*)d_in[3];
  const float* R      = (const float*)d_in[4];
  const float* bias   = (const float*)d_in[5];
  float* out = (float*)d_out;

  char* ws = (char*)d_ws;
  float* xp  = (float*)ws;                           // 50,331,648 B
  u16*   Rbf = (u16*)(ws + 50331648);                //  1,572,864 B

  dim3 gT(N3 / 64, NU / 64);
  rtrans_kernel<<<gT, 256, 0, stream>>>(R, Rbf);
  dim3 gA(N3 / 64, (NB * NS) / 64);
  xproj_kernel<<<gA, 256, 0, stream>>>(x, emb, W, bias, xp);
  gru_scan_kernel<<<4, 1024, 0, stream>>>(xp, hidden, Rbf, bias, out);
}